// Round 6
// baseline (315.433 us; speedup 1.0000x reference)
//
#include <hip/hip_runtime.h>

#define NX 160
#define NY 192
#define NZ 160
#define WIN 21
#define HALF 10
#define NTOT (NX * NY * NZ)     // 4,915,200
#define PLANE (NY * NZ)         // 30,720

// ---- K1 (z-pass) geometry ----
#define YB 16                   // y-rows per block
#define RS 196                  // LDS slab row stride (floats); data at +16; 196%32=4 -> 2-way max
#define DOFF 16                 // left slack so z-11 reads stay in-bounds
#define QRS 161                 // q row stride
#define QPL (16 * QRS + 8)      // 2584; 2584%32=24 -> fields spread across banks

// ---- K2 (y-pass, two-buffer variant) ----
#define YCH 32                  // y-chunk per block

// ---- K3 (x-pass) ----
#define XC 40                   // x-chunk per block

// ---------------------------------------------------------------------------
// K1: fused z-pass for all 5 fields (I, J, I2, J2, IJ).
// grid = (NX, NY/YB), block = 256
// ---------------------------------------------------------------------------
__global__ __launch_bounds__(256) void k_zpass(const float* __restrict__ I,
                                               const float* __restrict__ J,
                                               float* __restrict__ Bz) {
    __shared__ __align__(16) float sI[YB * RS];
    __shared__ __align__(16) float sJ[YB * RS];
    __shared__ float sQ[5 * QPL];

    const int bx = blockIdx.x;
    const int y0 = blockIdx.y * YB;
    const int tid = threadIdx.x;
    const size_t base = (size_t)bx * PLANE + (size_t)y0 * NZ;

    // ---- load I,J slabs (contiguous (y,z) region), float4 coalesced ----
    const float4* Ig = (const float4*)(I + base);
    const float4* Jg = (const float4*)(J + base);
    for (int i = tid; i < YB * NZ / 4; i += 256) {  // 640 float4s
        const int r = i / (NZ / 4);
        const int zc = i - r * (NZ / 4);
        *(float4*)&sI[r * RS + DOFF + 4 * zc] = Ig[i];
    }
    for (int i = tid; i < YB * NZ / 4; i += 256) {
        const int r = i / (NZ / 4);
        const int zc = i - r * (NZ / 4);
        *(float4*)&sJ[r * RS + DOFF + 4 * zc] = Jg[i];
    }
    __syncthreads();

    // ---- z running sums: 160 tasks = 16 rows x 5 fields x 2 z-chunks(80) ----
    if (tid < 160) {
        const int c = tid / 80;
        const int t = tid - c * 80;
        const int f = t / 16;
        const int r = t - f * 16;
        const float* Ir = sI + r * RS + DOFF;
        const float* Jr = sJ + r * RS + DOFF;
        float* qp = sQ + f * QPL + r * QRS;
        const int z0 = c * 80;

        float s = 0.0f;
#pragma unroll
        for (int k = -HALF; k <= HALF; ++k) {
            const int zi = z0 + k;
            const float a = Ir[zi];   // slack region reads are select-zeroed below
            const float b = Jr[zi];
            const float v = (f == 0) ? a : (f == 1) ? b : (f == 2) ? a * a
                          : (f == 3) ? b * b : a * b;
            s += (zi >= 0 && zi < NZ) ? v : 0.0f;
        }
        qp[z0] = s;
        for (int z = z0 + 1; z < z0 + 80; ++z) {
            const int za = z + HALF;
            const int zr = z - HALF - 1;
            const float Ia = Ir[za], Ja = Jr[za];
            const float Iv = Ir[zr], Jv = Jr[zr];
            float va = (f == 0) ? Ia : (f == 1) ? Ja : (f == 2) ? Ia * Ia
                     : (f == 3) ? Ja * Ja : Ia * Ja;
            float vr = (f == 0) ? Iv : (f == 1) ? Jv : (f == 2) ? Iv * Iv
                     : (f == 3) ? Jv * Jv : Iv * Jv;
            va = (za < NZ) ? va : 0.0f;
            vr = (zr >= 0) ? vr : 0.0f;
            s += va - vr;
            qp[z] = s;
        }
    }
    __syncthreads();

    // ---- cooperative coalesced write-out of all 5 field slabs ----
    for (int i = tid; i < 5 * YB * NZ; i += 256) {  // 12800 floats
        const int f = i / (YB * NZ);
        const int rem = i - f * (YB * NZ);
        const int r = rem / NZ;
        const int z = rem - r * NZ;
        Bz[(size_t)f * NTOT + base + (size_t)r * NZ + z] = sQ[f * QPL + r * QRS + z];
    }
}

// ---------------------------------------------------------------------------
// K2a: y-pass, two-buffer variant. Thread per (x,z) column, register running
// sums for 5 fields. Wave lanes = consecutive z -> fully coalesced.
// grid = (NX*NZ/256, NY/YCH), block 256
// ---------------------------------------------------------------------------
__global__ __launch_bounds__(256) void k_ypass(const float* __restrict__ Bz,
                                               float* __restrict__ Bzy) {
    const int col = blockIdx.x * 256 + threadIdx.x;  // < NX*NZ = 25600
    const int x = col / NZ;
    const int z = col - x * NZ;
    const int y0 = blockIdx.y * YCH;
    const size_t base = (size_t)x * PLANE + z;

    float s0 = 0.f, s1 = 0.f, s2 = 0.f, s3 = 0.f, s4 = 0.f;
#pragma unroll
    for (int k = -HALF; k <= HALF; ++k) {
        const int y = y0 + k;
        if (y >= 0 && y < NY) {
            const size_t o = base + (size_t)y * NZ;
            s0 += Bz[o];
            s1 += Bz[o + (size_t)NTOT];
            s2 += Bz[o + 2 * (size_t)NTOT];
            s3 += Bz[o + 3 * (size_t)NTOT];
            s4 += Bz[o + 4 * (size_t)NTOT];
        }
    }
    for (int j = 0; j < YCH; ++j) {
        const int y = y0 + j;
        const size_t o = base + (size_t)y * NZ;
        Bzy[o] = s0;
        Bzy[o + (size_t)NTOT] = s1;
        Bzy[o + 2 * (size_t)NTOT] = s2;
        Bzy[o + 3 * (size_t)NTOT] = s3;
        Bzy[o + 4 * (size_t)NTOT] = s4;
        const int ya = y + HALF + 1;
        const int yr = y - HALF;
        if (ya < NY) {
            const size_t oa = base + (size_t)ya * NZ;
            s0 += Bz[oa];
            s1 += Bz[oa + (size_t)NTOT];
            s2 += Bz[oa + 2 * (size_t)NTOT];
            s3 += Bz[oa + 3 * (size_t)NTOT];
            s4 += Bz[oa + 4 * (size_t)NTOT];
        }
        if (yr >= 0) {
            const size_t orr = base + (size_t)yr * NZ;
            s0 -= Bz[orr];
            s1 -= Bz[orr + (size_t)NTOT];
            s2 -= Bz[orr + 2 * (size_t)NTOT];
            s3 -= Bz[orr + 3 * (size_t)NTOT];
            s4 -= Bz[orr + 4 * (size_t)NTOT];
        }
    }
}

// ---------------------------------------------------------------------------
// K2b: y-pass IN PLACE, single-buffer variant. One block per (x-slice, field);
// whole 192x160 slice in LDS (122.9 KB, legal on gfx950 160KB/CU), y-filter
// into registers, coalesced write-back. No cross-block dependency (y-filter
// never leaves the x-slice). grid = (NX, 5), block = 1024
// ---------------------------------------------------------------------------
__global__ __launch_bounds__(1024) void k_ypass_inplace(float* __restrict__ B) {
    __shared__ float s[PLANE];  // 30720 floats = 122.88 KB
    const int bx = blockIdx.x;
    const int f = blockIdx.y;
    float* base = B + (size_t)f * NTOT + (size_t)bx * PLANE;
    const int tid = threadIdx.x;

    const float4* g4 = (const float4*)base;
    for (int i = tid; i < PLANE / 4; i += 1024) ((float4*)s)[i] = g4[i];
    __syncthreads();

    // 960 tasks: z in [0,160) x 6 y-chunks of 32. Lanes -> consecutive z.
    if (tid < 960) {
        const int z = tid % NZ;
        const int c = tid / NZ;
        const int y0 = c * 32;

        float sum = 0.0f;
#pragma unroll
        for (int k = -HALF; k <= HALF; ++k) {
            const int y = y0 + k;
            if (y >= 0 && y < NY) sum += s[y * NZ + z];
        }
        float out[32];
#pragma unroll
        for (int j = 0; j < 32; ++j) {
            out[j] = sum;
            const int ya = y0 + j + HALF + 1;
            const int yr = y0 + j - HALF;
            if (ya < NY) sum += s[ya * NZ + z];
            if (yr >= 0) sum -= s[yr * NZ + z];
        }
        // write back in place; per wave at fixed j the 64 lanes hit
        // consecutive z -> coalesced 256B segments
#pragma unroll
        for (int j = 0; j < 32; ++j) base[(size_t)(y0 + j) * NZ + z] = out[j];
    }
}

// ---------------------------------------------------------------------------
// K3: x-pass + cc + reduction. Thread per (y,z) column, running sums along x.
// grid = (NY*NZ/256, NX/XC), block = 256
// ---------------------------------------------------------------------------
__global__ __launch_bounds__(256) void pass_x_cc(const float* __restrict__ B,
                                                 float* __restrict__ acc) {
    const int SX = PLANE;
    const int col = blockIdx.x * 256 + threadIdx.x;  // (y*NZ + z)
    const int x0 = blockIdx.y * XC;

    const float* b0 = B + col;
    const float* b1 = b0 + (size_t)NTOT;
    const float* b2 = b1 + (size_t)NTOT;
    const float* b3 = b2 + (size_t)NTOT;
    const float* b4 = b3 + (size_t)NTOT;

    float sI = 0.f, sJ = 0.f, sI2 = 0.f, sJ2 = 0.f, sIJ = 0.f;
#pragma unroll
    for (int k = -HALF; k <= HALF; ++k) {
        const int xx = x0 + k;
        if (xx >= 0 && xx < NX) {
            const int o = xx * SX;
            sI += b0[o]; sJ += b1[o]; sI2 += b2[o]; sJ2 += b3[o]; sIJ += b4[o];
        }
    }

    const float n = (float)(WIN * WIN * WIN);
    const float inv_n = 1.0f / n;
    float local = 0.0f;
#pragma unroll 2
    for (int j = 0; j < XC; ++j) {
        const int x = x0 + j;
        const float uI = sI * inv_n;
        const float uJ = sJ * inv_n;
        const float cross = sIJ - uJ * sI - uI * sJ + uI * uJ * n;
        const float Ivar = sI2 - 2.0f * uI * sI + uI * uI * n;
        const float Jvar = sJ2 - 2.0f * uJ * sJ + uJ * uJ * n;
        local += cross * cross / (Ivar * Jvar + 1e-5f);
        const int xa = x + HALF + 1;
        const int xr = x - HALF;
        if (xa < NX) {
            const int o = xa * SX;
            sI += b0[o]; sJ += b1[o]; sI2 += b2[o]; sJ2 += b3[o]; sIJ += b4[o];
        }
        if (xr >= 0) {
            const int o = xr * SX;
            sI -= b0[o]; sJ -= b1[o]; sI2 -= b2[o]; sJ2 -= b3[o]; sIJ -= b4[o];
        }
    }

    const int lane = threadIdx.x & 63;
    const int wid = threadIdx.x >> 6;
    for (int off = 32; off; off >>= 1) local += __shfl_down(local, off);
    __shared__ float red[4];
    if (lane == 0) red[wid] = local;
    __syncthreads();
    if (threadIdx.x == 0) {
        atomicAdd(acc, red[0] + red[1] + red[2] + red[3]);
    }
}

__global__ void finalize_k(const float* __restrict__ acc, float* __restrict__ out) {
    out[0] = 1.0f - acc[0] / (float)NTOT;
}

extern "C" void kernel_launch(void* const* d_in, const int* in_sizes, int n_in,
                              void* d_out, int out_size, void* d_ws, size_t ws_size,
                              hipStream_t stream) {
    const float* I = (const float*)d_in[0];
    const float* J = (const float*)d_in[1];
    float* out = (float*)d_out;

    float* acc = (float*)d_ws;                                   // accumulator
    float* Bz = (float*)((char*)d_ws + 256);                     // 5*NTOT f32

    hipMemsetAsync(d_ws, 0, 256, stream);

    dim3 g1(NX, NY / YB);                 // (160, 12)
    k_zpass<<<g1, 256, 0, stream>>>(I, J, Bz);

    const size_t need2 = 256 + 10ULL * NTOT * 4;  // two 5-field buffers
    if (ws_size >= need2) {
        // fast path: separate Bzy buffer, streaming y-pass
        float* Bzy = Bz + 5L * NTOT;
        dim3 g2(NX * NZ / 256, NY / YCH); // (100, 6)
        k_ypass<<<g2, 256, 0, stream>>>(Bz, Bzy);
        dim3 g3(PLANE / 256, NX / XC);    // (120, 4)
        pass_x_cc<<<g3, 256, 0, stream>>>(Bzy, acc);
    } else {
        // single-buffer path: in-place y-pass (needs only 98.3 MB, proven in R0)
        dim3 g2(NX, 5);
        k_ypass_inplace<<<g2, 1024, 0, stream>>>(Bz);
        dim3 g3(PLANE / 256, NX / XC);    // (120, 4)
        pass_x_cc<<<g3, 256, 0, stream>>>(Bz, acc);
    }

    finalize_k<<<1, 1, 0, stream>>>(acc, out);
}

// Round 7
// 217.814 us; speedup vs baseline: 1.4482x; 1.4482x over previous
//
#include <hip/hip_runtime.h>

#define NX 160
#define NY 192
#define NZ 160
#define WIN 21
#define HALF 10
#define NTOT (NX * NY * NZ)     // 4,915,200
#define PLANE (NY * NZ)         // 30,720

// ---- K1 (z-pass, register-based) ----
#define ZOUT 16                 // z outputs per thread
#define ZTH (NZ / ZOUT)         // 10 threads per (x,y) row

// ---- K2 (y-pass, two-buffer variant) ----
#define YCH 16                  // y-chunk per block (12 chunks -> 1200 blocks)

// ---- K3 (x-pass) ----
#define XC 20                   // x-chunk per block (8 chunks -> 960 blocks)

// ---------------------------------------------------------------------------
// K1: fused z-pass for all 5 fields (I, J, I2, J2, IJ) — pure-register.
// Each thread: one (x,y) row, 16 consecutive z outputs. 40-float window per
// field via 10 clamped float4 loads (window vectors are fully in- or out-of-
// range because NZ%4==0 and offsets are 4-aligned). No LDS, no barriers.
// grid = NX*NY*ZTH/256 = 1200, block = 256
// ---------------------------------------------------------------------------
__global__ __launch_bounds__(256) void k_zpass_reg(const float* __restrict__ I,
                                                   const float* __restrict__ J,
                                                   float* __restrict__ Bz) {
    const int t = blockIdx.x * 256 + threadIdx.x;   // < 307200 exact
    const int zc = t % ZTH;
    const int row = t / ZTH;                        // x*NY + y
    const int z0 = zc * ZOUT;
    const size_t rbase = (size_t)row * NZ;

    // window array idx = z - z0 + 12; valid data idx 2..37; 0,1,38,39 slack
    float aI[40], aJ[40];
#pragma unroll
    for (int k = 0; k < 10; ++k) {
        const int b = z0 - 12 + 4 * k;
        const int bc = b < 0 ? 0 : (b > NZ - 4 ? NZ - 4 : b);   // always in-buffer
        const float4 vI = *(const float4*)(I + rbase + bc);
        const float4 vJ = *(const float4*)(J + rbase + bc);
        const float m = (b == bc) ? 1.0f : 0.0f;    // zero-pad outside [0,NZ)
        aI[4*k+0] = m * vI.x; aI[4*k+1] = m * vI.y;
        aI[4*k+2] = m * vI.z; aI[4*k+3] = m * vI.w;
        aJ[4*k+0] = m * vJ.x; aJ[4*k+1] = m * vJ.y;
        aJ[4*k+2] = m * vJ.z; aJ[4*k+3] = m * vJ.w;
    }

    // initial 21-tap window for output z0: d = -10..10 -> idx 2..22
    float s0 = 0.f, s1 = 0.f, s2 = 0.f, s3 = 0.f, s4 = 0.f;
#pragma unroll
    for (int d = 2; d <= 22; ++d) {
        const float a = aI[d], b = aJ[d];
        s0 += a; s1 += b;
        s2 = fmaf(a, a, s2); s3 = fmaf(b, b, s3); s4 = fmaf(a, b, s4);
    }

    float ob[5][4];
#pragma unroll
    for (int j = 0; j < ZOUT; ++j) {
        if (j > 0) {
            const float Aa = aI[j + 22], Ba = aJ[j + 22];  // entering z0+j+10
            const float Ar = aI[j + 1],  Br = aJ[j + 1];   // leaving  z0+j-11
            s0 += Aa - Ar;
            s1 += Ba - Br;
            s2 += Aa * Aa - Ar * Ar;
            s3 += Ba * Ba - Br * Br;
            s4 += Aa * Ba - Ar * Br;
        }
        const int e = j & 3;
        ob[0][e] = s0; ob[1][e] = s1; ob[2][e] = s2; ob[3][e] = s3; ob[4][e] = s4;
        if (e == 3) {
            const size_t o = rbase + (size_t)(z0 + j - 3);
#pragma unroll
            for (int f = 0; f < 5; ++f) {
                *(float4*)(Bz + (size_t)f * NTOT + o) =
                    make_float4(ob[f][0], ob[f][1], ob[f][2], ob[f][3]);
            }
        }
    }
}

// ---------------------------------------------------------------------------
// K2a: y-pass, two-buffer variant. Thread per (x,z) column, register running
// sums for 5 fields. Wave lanes = consecutive z -> fully coalesced.
// grid = (NX*NZ/256, NY/YCH) = (100, 12), block 256
// ---------------------------------------------------------------------------
__global__ __launch_bounds__(256) void k_ypass(const float* __restrict__ Bz,
                                               float* __restrict__ Bzy) {
    const int col = blockIdx.x * 256 + threadIdx.x;  // < NX*NZ = 25600
    const int x = col / NZ;
    const int z = col - x * NZ;
    const int y0 = blockIdx.y * YCH;
    const size_t base = (size_t)x * PLANE + z;

    float s0 = 0.f, s1 = 0.f, s2 = 0.f, s3 = 0.f, s4 = 0.f;
#pragma unroll
    for (int k = -HALF; k <= HALF; ++k) {
        const int y = y0 + k;
        if (y >= 0 && y < NY) {
            const size_t o = base + (size_t)y * NZ;
            s0 += Bz[o];
            s1 += Bz[o + (size_t)NTOT];
            s2 += Bz[o + 2 * (size_t)NTOT];
            s3 += Bz[o + 3 * (size_t)NTOT];
            s4 += Bz[o + 4 * (size_t)NTOT];
        }
    }
    for (int j = 0; j < YCH; ++j) {
        const int y = y0 + j;
        const size_t o = base + (size_t)y * NZ;
        Bzy[o] = s0;
        Bzy[o + (size_t)NTOT] = s1;
        Bzy[o + 2 * (size_t)NTOT] = s2;
        Bzy[o + 3 * (size_t)NTOT] = s3;
        Bzy[o + 4 * (size_t)NTOT] = s4;
        const int ya = y + HALF + 1;
        const int yr = y - HALF;
        if (ya < NY) {
            const size_t oa = base + (size_t)ya * NZ;
            s0 += Bz[oa];
            s1 += Bz[oa + (size_t)NTOT];
            s2 += Bz[oa + 2 * (size_t)NTOT];
            s3 += Bz[oa + 3 * (size_t)NTOT];
            s4 += Bz[oa + 4 * (size_t)NTOT];
        }
        if (yr >= 0) {
            const size_t orr = base + (size_t)yr * NZ;
            s0 -= Bz[orr];
            s1 -= Bz[orr + (size_t)NTOT];
            s2 -= Bz[orr + 2 * (size_t)NTOT];
            s3 -= Bz[orr + 3 * (size_t)NTOT];
            s4 -= Bz[orr + 4 * (size_t)NTOT];
        }
    }
}

// ---------------------------------------------------------------------------
// K2b: y-pass IN PLACE, single-buffer fallback. Block owns (x-slice, field,
// z-chunk of 32): LDS 192x32 floats = 24.6 KB -> 6 blocks/CU, 4000 blocks.
// In-place safe: y-filter never leaves the (x, z-chunk) tile.
// grid = (NX, 5, NZ/32), block = 256
// ---------------------------------------------------------------------------
__global__ __launch_bounds__(256) void k_ypass_inplace(float* __restrict__ B) {
    __shared__ float s[NY][32];
    const int x = blockIdx.x;
    const int f = blockIdx.y;
    const int z0 = blockIdx.z * 32;
    float* base = B + (size_t)f * NTOT + (size_t)x * PLANE + z0;
    const int tid = threadIdx.x;

    for (int i = tid; i < NY * 8; i += 256) {        // 1536 float4s
        const int y = i / 8;
        const int zc = i - y * 8;
        *(float4*)&s[y][4 * zc] = *(const float4*)(base + (size_t)y * NZ + 4 * zc);
    }
    __syncthreads();

    if (tid < 192) {                                  // 32 z x 6 y-chunks
        const int zz = tid & 31;
        const int y0 = (tid >> 5) * 32;
        float sum = 0.0f;
#pragma unroll
        for (int k = -HALF; k <= HALF; ++k) {
            const int y = y0 + k;
            if (y >= 0 && y < NY) sum += s[y][zz];
        }
        float out[32];
#pragma unroll
        for (int j = 0; j < 32; ++j) {
            out[j] = sum;
            const int ya = y0 + j + HALF + 1;
            const int yr = y0 + j - HALF;
            if (ya < NY) sum += s[ya][zz];
            if (yr >= 0) sum -= s[yr][zz];
        }
#pragma unroll
        for (int j = 0; j < 32; ++j) base[(size_t)(y0 + j) * NZ + zz] = out[j];
    }
}

// ---------------------------------------------------------------------------
// K3: x-pass + cc + reduction. Thread per (y,z) column, running sums along x.
// grid = (PLANE/256, NX/XC) = (120, 8), block = 256
// ---------------------------------------------------------------------------
__global__ __launch_bounds__(256) void pass_x_cc(const float* __restrict__ B,
                                                 float* __restrict__ acc) {
    const int SX = PLANE;
    const int col = blockIdx.x * 256 + threadIdx.x;  // (y*NZ + z)
    const int x0 = blockIdx.y * XC;

    const float* b0 = B + col;
    const float* b1 = b0 + (size_t)NTOT;
    const float* b2 = b1 + (size_t)NTOT;
    const float* b3 = b2 + (size_t)NTOT;
    const float* b4 = b3 + (size_t)NTOT;

    float sI = 0.f, sJ = 0.f, sI2 = 0.f, sJ2 = 0.f, sIJ = 0.f;
#pragma unroll
    for (int k = -HALF; k <= HALF; ++k) {
        const int xx = x0 + k;
        if (xx >= 0 && xx < NX) {
            const int o = xx * SX;
            sI += b0[o]; sJ += b1[o]; sI2 += b2[o]; sJ2 += b3[o]; sIJ += b4[o];
        }
    }

    const float n = (float)(WIN * WIN * WIN);
    const float inv_n = 1.0f / n;
    float local = 0.0f;
#pragma unroll 2
    for (int j = 0; j < XC; ++j) {
        const int x = x0 + j;
        const float uI = sI * inv_n;
        const float uJ = sJ * inv_n;
        const float cross = sIJ - uJ * sI - uI * sJ + uI * uJ * n;
        const float Ivar = sI2 - 2.0f * uI * sI + uI * uI * n;
        const float Jvar = sJ2 - 2.0f * uJ * sJ + uJ * uJ * n;
        local += cross * cross / (Ivar * Jvar + 1e-5f);
        const int xa = x + HALF + 1;
        const int xr = x - HALF;
        if (xa < NX) {
            const int o = xa * SX;
            sI += b0[o]; sJ += b1[o]; sI2 += b2[o]; sJ2 += b3[o]; sIJ += b4[o];
        }
        if (xr >= 0) {
            const int o = xr * SX;
            sI -= b0[o]; sJ -= b1[o]; sI2 -= b2[o]; sJ2 -= b3[o]; sIJ -= b4[o];
        }
    }

    const int lane = threadIdx.x & 63;
    const int wid = threadIdx.x >> 6;
    for (int off = 32; off; off >>= 1) local += __shfl_down(local, off);
    __shared__ float red[4];
    if (lane == 0) red[wid] = local;
    __syncthreads();
    if (threadIdx.x == 0) {
        atomicAdd(acc, red[0] + red[1] + red[2] + red[3]);
    }
}

__global__ void finalize_k(const float* __restrict__ acc, float* __restrict__ out) {
    out[0] = 1.0f - acc[0] / (float)NTOT;
}

extern "C" void kernel_launch(void* const* d_in, const int* in_sizes, int n_in,
                              void* d_out, int out_size, void* d_ws, size_t ws_size,
                              hipStream_t stream) {
    const float* I = (const float*)d_in[0];
    const float* J = (const float*)d_in[1];
    float* out = (float*)d_out;

    float* acc = (float*)d_ws;                                   // accumulator
    float* Bz = (float*)((char*)d_ws + 256);                     // 5*NTOT f32

    hipMemsetAsync(d_ws, 0, 256, stream);

    k_zpass_reg<<<NX * NY * ZTH / 256, 256, 0, stream>>>(I, J, Bz);  // 1200 blocks

    const size_t need2 = 256 + 10ULL * NTOT * 4;  // two 5-field buffers
    if (ws_size >= need2) {
        // fast path: separate Bzy buffer, streaming y-pass
        float* Bzy = Bz + 5L * NTOT;
        dim3 g2(NX * NZ / 256, NY / YCH); // (100, 12)
        k_ypass<<<g2, 256, 0, stream>>>(Bz, Bzy);
        dim3 g3(PLANE / 256, NX / XC);    // (120, 8)
        pass_x_cc<<<g3, 256, 0, stream>>>(Bzy, acc);
    } else {
        // single-buffer path: in-place y-pass (needs only 98.3 MB, proven in R0)
        dim3 g2(NX, 5, NZ / 32);          // 4000 blocks
        k_ypass_inplace<<<g2, 256, 0, stream>>>(Bz);
        dim3 g3(PLANE / 256, NX / XC);    // (120, 8)
        pass_x_cc<<<g3, 256, 0, stream>>>(Bz, acc);
    }

    finalize_k<<<1, 1, 0, stream>>>(acc, out);
}